// Round 6
// baseline (3438.185 us; speedup 1.0000x reference)
//
#include <hip/hip_runtime.h>

typedef float f4 __attribute__((ext_vector_type(4)));
typedef _Float16 h8v __attribute__((ext_vector_type(8)));
typedef float f32x4 __attribute__((ext_vector_type(4)));

static constexpr int NB = 128, NT = 4096, NI = 64, NH = 256, NO = 64;
static constexpr int CPB = 4;            // chains per block
static constexpr int NBLK = NB / CPB;    // 32 blocks

union I4H8 { int4 i; h8v h; };
union H2I2 { int i; _Float16 h[2]; };

__device__ __forceinline__ int pk2(float a, float b) {
    H2I2 u; u.h[0] = (_Float16)a; u.h[1] = (_Float16)b; return u.i;
}
__device__ __forceinline__ h8v pack8(f4 lo, f4 hi) {
    h8v r;
    r[0] = (_Float16)lo.x; r[1] = (_Float16)lo.y; r[2] = (_Float16)lo.z; r[3] = (_Float16)lo.w;
    r[4] = (_Float16)hi.x; r[5] = (_Float16)hi.y; r[6] = (_Float16)hi.z; r[7] = (_Float16)hi.w;
    return r;
}
__device__ __forceinline__ float ror4f(float v) {
    return __int_as_float(__builtin_amdgcn_mov_dpp(__float_as_int(v), 0x124, 0xF, 0xF, true));
}
__device__ __forceinline__ float ror8f(float v) {
    return __int_as_float(__builtin_amdgcn_mov_dpp(__float_as_int(v), 0x128, 0xF, 0xF, true));
}
__device__ __forceinline__ float ror12f(float v) {
    return __int_as_float(__builtin_amdgcn_mov_dpp(__float_as_int(v), 0x12C, 0xF, 0xF, true));
}
__device__ __forceinline__ f32x4 mfma16(h8v a, h8v b, f32x4 c) {
    return __builtin_amdgcn_mfma_f32_16x16x32_f16(a, b, c, 0, 0, 0);
}
__device__ __forceinline__ float fast_tanh(float x) {
    float e = __builtin_amdgcn_exp2f(x * 2.885390081777927f); // 2*log2(e)
    return 1.0f - 2.0f * __builtin_amdgcn_rcpf(e + 1.0f);
}

// One block = 4 chains. C[256 rows][16 cols] = Whh*h + Wih*x via mfma 16x16x32 f16.
// LDS h/x stored in B-fragment order: slot(l)= (l&3)+4*(l>>4), 16B = {k0..k0+3, k0+16..k0+19}
// with k0 = kt*32 + (l>>4)*4, col = l&3 (cols 4-15 broadcast-duplicate cols 0-3).
__global__ __launch_bounds__(256, 1) void rnn_mfma(
    const float* __restrict__ x,    // [B,T,I] f32
    const float* __restrict__ wih,  // [H,I]
    const float* __restrict__ whh,  // [H,H]
    const float* __restrict__ bih,  // [H]
    const float* __restrict__ bhh,  // [H]
    const float* __restrict__ wy,   // [O,H]
    const float* __restrict__ by,   // [O]
    float* __restrict__ out)        // [B,O]
{
    __shared__ int hb[2][512];    // h B-frags: 8 kt * 16 slots * 16B = 2KB per buffer
    __shared__ int xb[2][2048];   // x B-frags: 16 t * 2 kt * 16 slots * 16B = 8KB per buffer
    __shared__ float hf[CPB * NH];

    const int tid = threadIdx.x;
    const int w = tid >> 6;          // wave: M-tiles 4w..4w+3 (rows 64w..64w+63)
    const int l = tid & 63;
    const int c0 = l & 3;            // real col (chain)
    const int p4 = (l >> 2) & 3;     // compaction slot
    const int a = l >> 4;            // k-group
    const int b0 = blockIdx.x * CPB;

    // ---- cold: A fragments in registers ----
    h8v Ah[4][8];   // Whh[64w+16mt+(l&15)][kt*32 + a*4 .. +3, +16..+19]
    h8v Axf[4][2];  // Wih rows, K=64 (2 K-tiles)
    float biasv[4];
    int pub_off[4], hf_off[4];
#pragma unroll
    for (int mt = 0; mt < 4; ++mt) {
        const int row = 64 * w + 16 * mt + (l & 15);
#pragma unroll
        for (int kt = 0; kt < 8; ++kt) {
            const f4* pr = (const f4*)(whh + (size_t)row * NH + kt * 32 + a * 4);
            Ah[mt][kt] = pack8(pr[0], pr[4]);
        }
#pragma unroll
        for (int kt = 0; kt < 2; ++kt) {
            const f4* pr = (const f4*)(wih + (size_t)row * NI + kt * 32 + a * 4);
            Axf[mt][kt] = pack8(pr[0], pr[4]);
        }
        const int R = 64 * w + 16 * mt + 4 * a + p4;  // row this lane owns post-compaction
        biasv[mt] = bih[R] + bhh[R];
        // publish addr: kt = R>>5, slot = c0 + 4*((R>>2)&3) = c0+4a, byte = ((R>>4)&1)*8 + (R&3)*2
        pub_off[mt] = (2 * w + (mt >> 1)) * 256 + (c0 + 4 * a) * 16 + (mt & 1) * 8 + p4 * 2;
        hf_off[mt] = c0 * NH + R;
    }
    const int rdo = (c0 + 4 * a) * 16;  // B-frag read slot offset (bytes)

    // ---- x staging map: thread -> (chain tc, step tt, k-quad tk) ----
    const int tc = tid >> 6;
    const int tt = (tid >> 2) & 15;
    const int tk = tid & 3;  // k0 = tk*16
    int cmo[4];
#pragma unroll
    for (int u = 0; u < 4; ++u)
        cmo[u] = (tt * 2 + (tk >> 1)) * 256 + (tc + 4 * u) * 16 + (tk & 1) * 8;

    // stage chunk 0
    f4 ld[4];
    {
        const float* xrow = x + ((size_t)(b0 + tc) * NT + tt) * NI + tk * 16;
#pragma unroll
        for (int u = 0; u < 4; ++u) ld[u] = ((const f4*)xrow)[u];
        char* xw = (char*)xb[0];
#pragma unroll
        for (int u = 0; u < 4; ++u) {
            int2 pk; pk.x = pk2(ld[u].x, ld[u].y); pk.y = pk2(ld[u].z, ld[u].w);
            *(int2*)(xw + cmo[u]) = pk;
        }
    }
    if (tid < 128) ((int4*)hb[0])[tid] = int4{0, 0, 0, 0};  // h(0)=0
    __syncthreads();

    int pp = 0;
#pragma unroll 1
    for (int t = 0; t < NT; ++t) {
        const int s = t & 15;
        const int cb = (t >> 4) & 1;

        if (s == 0 && t + 16 < NT) {
            const float* xrow = x + ((size_t)(b0 + tc) * NT + (t + 16) + tt) * NI + tk * 16;
#pragma unroll
            for (int u = 0; u < 4; ++u) ld[u] = ((const f4*)xrow)[u];
        }

        // B-fragment reads
        const char* hbp = (const char*)hb[pp];
        int4 bh[8];
#pragma unroll
        for (int kt = 0; kt < 8; ++kt) bh[kt] = *(const int4*)(hbp + kt * 256 + rdo);
        const char* xbp = (const char*)xb[cb] + s * 512;
        const int4 bx0 = *(const int4*)(xbp + rdo);
        const int4 bx1 = *(const int4*)(xbp + 256 + rdo);

        f32x4 acc[4];
#pragma unroll
        for (int mt = 0; mt < 4; ++mt) acc[mt] = f32x4{0.f, 0.f, 0.f, 0.f};

        // recurrent part: 32 MFMA, 4-tile round robin per K-tile
#pragma unroll
        for (int kt = 0; kt < 8; ++kt) {
            I4H8 u; u.i = bh[kt];
            acc[0] = mfma16(Ah[0][kt], u.h, acc[0]);
            acc[1] = mfma16(Ah[1][kt], u.h, acc[1]);
            acc[2] = mfma16(Ah[2][kt], u.h, acc[2]);
            acc[3] = mfma16(Ah[3][kt], u.h, acc[3]);
        }
        // input part: 8 MFMA
        {
            I4H8 u0, u1; u0.i = bx0; u1.i = bx1;
#pragma unroll
            for (int mt = 0; mt < 4; ++mt) {
                acc[mt] = mfma16(Axf[mt][0], u0.h, acc[mt]);
                acc[mt] = mfma16(Axf[mt][1], u1.h, acc[mt]);
            }
        }

        // tails: compact 4 regs -> 1 real value/lane, bias+tanh, publish fp16
        char* hbw = (char*)hb[pp ^ 1];
#pragma unroll
        for (int mt = 0; mt < 4; ++mt) {
            const float v0 = acc[mt][0];
            const float ra = ror12f(acc[mt][1]);  // lanes 4-7   <- 0-3
            const float rb = ror8f(acc[mt][2]);   // lanes 8-11  <- 0-3
            const float rc = ror4f(acc[mt][3]);   // lanes 12-15 <- 0-3
            const float sv = (p4 == 0) ? v0 : (p4 == 1) ? ra : (p4 == 2) ? rb : rc;
            const float th = fast_tanh(sv + biasv[mt]);
            *(_Float16*)(hbw + pub_off[mt]) = (_Float16)th;
            if (t == NT - 1) hf[hf_off[mt]] = th;
        }

        // commit prefetched x chunk
        if (s == 15 && t + 1 < NT) {
            char* xw = (char*)xb[cb ^ 1];
#pragma unroll
            for (int u = 0; u < 4; ++u) {
                int2 pk; pk.x = pk2(ld[u].x, ld[u].y); pk.y = pk2(ld[u].z, ld[u].w);
                *(int2*)(xw + cmo[u]) = pk;
            }
        }

        __syncthreads();
        pp ^= 1;
    }

    // ---- epilogue: y = h_last @ Wy^T + by ----
    {
        const int c = tid >> 6, o = tid & 63;
        float accy = by[o];
        const f4* wr = (const f4*)(wy + (size_t)o * NH);
        const f4* hp = (const f4*)&hf[c * NH];
#pragma unroll
        for (int u = 0; u < NH / 4; ++u) {
            f4 wv = wr[u]; f4 hv = hp[u];
            accy += wv.x * hv.x + wv.y * hv.y + wv.z * hv.z + wv.w * hv.w;
        }
        out[(b0 + c) * NO + o] = accy;
    }
}

extern "C" void kernel_launch(void* const* d_in, const int* in_sizes, int n_in,
                              void* d_out, int out_size, void* d_ws, size_t ws_size,
                              hipStream_t stream) {
    const float* x   = (const float*)d_in[0];
    const float* wih = (const float*)d_in[1];
    const float* whh = (const float*)d_in[2];
    const float* bih = (const float*)d_in[3];
    const float* bhh = (const float*)d_in[4];
    const float* wy  = (const float*)d_in[5];
    const float* by  = (const float*)d_in[6];
    float* out = (float*)d_out;

    rnn_mfma<<<dim3(NBLK), dim3(256), 0, stream>>>(x, wih, whh, bih, bhh, wy, by, out);
}